// Round 3
// baseline (322.942 us; speedup 1.0000x reference)
//
#include <hip/hip_runtime.h>

#define NU 8192
#define NI 8192
#define DD 128
#define ROWS 16

typedef float fx4 __attribute__((ext_vector_type(4)));
typedef int   ix4 __attribute__((ext_vector_type(4)));
typedef short bx8 __attribute__((ext_vector_type(8)));
typedef short sx4 __attribute__((ext_vector_type(4)));

__device__ __forceinline__ short f2bf(float f) {
  unsigned u = __float_as_uint(f);
  u = (u + 0x7FFFu + ((u >> 16) & 1u)) >> 16;   // RNE f32 -> bf16
  return (short)u;
}

__device__ __forceinline__ float lrelu(float x) { return fmaxf(x, 0.2f * x); }

// ---- K1: v1[j] = sum_k a[k]*W[k][j] ; v2[j] = sum_k a[128+k]*W[k][j]
__global__ void k_vecs(const float* __restrict__ W, const float* __restrict__ a,
                       float* __restrict__ v1, float* __restrict__ v2) {
  int j = threadIdx.x;  // 128 threads
  float s1 = 0.f, s2 = 0.f;
  for (int k = 0; k < DD; ++k) {
    float w = W[k * DD + j];
    s1 += a[k] * w;
    s2 += a[DD + k] * w;
  }
  v1[j] = s1; v2[j] = s2;
}

// ---- K2: a1[u] = h_u[u]·v1 ; a2[i] = h_i[i]·v2
__global__ void k_rowdots(const float* __restrict__ hU, const float* __restrict__ hI,
                          const float* __restrict__ v1, const float* __restrict__ v2,
                          float* __restrict__ a1, float* __restrict__ a2) {
  int g = blockIdx.x * 256 + threadIdx.x;
  const float* h; const float* v; float* dst; int row;
  if (g < NU) { h = hU; v = v1; dst = a1; row = g; }
  else        { h = hI; v = v2; dst = a2; row = g - NU; }
  const fx4* hv = (const fx4*)(h + (size_t)row * DD);
  const fx4* vv = (const fx4*)v;
  float s = 0.f;
#pragma unroll
  for (int q = 0; q < DD / 4; ++q) {
    fx4 hq = hv[q], vq = vv[q];
    s += hq[0]*vq[0] + hq[1]*vq[1] + hq[2]*vq[2] + hq[3]*vq[3];
  }
  dst[row] = s;
}

// ---- K3: global max of a2 (single block, deterministic)
__global__ void k_maxa2(const float* __restrict__ a2, float* __restrict__ mx) {
  __shared__ float red[256];
  float m = -3.0e38f;
  for (int i = threadIdx.x; i < NI; i += 256) m = fmaxf(m, a2[i]);
  red[threadIdx.x] = m;
  __syncthreads();
  for (int s = 128; s > 0; s >>= 1) {
    if (threadIdx.x < s) red[threadIdx.x] = fmaxf(red[threadIdx.x], red[threadIdx.x + s]);
    __syncthreads();
  }
  if (threadIdx.x == 0) mx[0] = red[0];
}

// ---- K4: WiT[k][i] (bf16) = Wi[i][k] = sum_j h_i[i][j]*W[k][j]
__global__ __launch_bounds__(256) void k_wit(const float* __restrict__ hI,
                                             const float* __restrict__ W,
                                             short* __restrict__ WiT) {
  __shared__ float Wl[128 * 128];
  const int tid = threadIdx.x;
#pragma unroll
  for (int it = 0; it < 16; ++it) {
    int idx = it * 1024 + tid * 4;
    *(fx4*)(Wl + idx) = *(const fx4*)(W + idx);
  }
  __syncthreads();
  const int i0 = blockIdx.x * 64;
  const int rg = tid & 15;
  const int kg = tid >> 4;
  const int r0 = i0 + rg * 4;
  const int k0 = kg * 8;
  float acc[4][8];
#pragma unroll
  for (int r = 0; r < 4; ++r)
#pragma unroll
    for (int c = 0; c < 8; ++c) acc[r][c] = 0.f;
  for (int j = 0; j < 128; j += 4) {
    fx4 wv[8], hv[4];
#pragma unroll
    for (int c = 0; c < 8; ++c) wv[c] = *(const fx4*)(Wl + (k0 + c) * 128 + j);
#pragma unroll
    for (int r = 0; r < 4; ++r) hv[r] = *(const fx4*)(hI + (size_t)(r0 + r) * DD + j);
#pragma unroll
    for (int r = 0; r < 4; ++r)
#pragma unroll
      for (int c = 0; c < 8; ++c)
        acc[r][c] += hv[r][0]*wv[c][0] + hv[r][1]*wv[c][1] + hv[r][2]*wv[c][2] + hv[r][3]*wv[c][3];
  }
#pragma unroll
  for (int c = 0; c < 8; ++c) {
    sx4 pk;
#pragma unroll
    for (int r = 0; r < 4; ++r) pk[r] = f2bf(acc[r][c]);
    *(sx4*)(WiT + (size_t)(k0 + c) * NI + r0) = pk;
  }
}

// ---- K5a: stream adj once -> bitmask[8192][256] + rinv[8192]
// one block (256 thr) per u-row; thread tid owns i in [tid*32, tid*32+32)
__global__ __launch_bounds__(256) void k_phaseA(
    const int* __restrict__ adj, const float* __restrict__ a1g,
    const float* __restrict__ a2g, const float* __restrict__ mxp,
    float* __restrict__ rinv, unsigned* __restrict__ mask)
{
  const int row = blockIdx.x;
  const int tid = threadIdx.x;
  const float a1u = a1g[row];
  const float C = lrelu(a1u + mxp[0]);   // >= masked row max (lrelu monotone)
  const int i0 = tid * 32;
  const size_t base = (size_t)row * NI + i0;
  unsigned word = 0u;
  float ps = 0.f;
#pragma unroll
  for (int q = 0; q < 8; ++q) {
    ix4 mv = *(const ix4*)(adj + base + q * 4);
    fx4 av = *(const fx4*)(a2g + i0 + q * 4);
#pragma unroll
    for (int e = 0; e < 4; ++e) {
      float p = __expf(lrelu(a1u + av[e]) - C);
      if (mv[e] != 0) { ps += p; word |= (1u << (q * 4 + e)); }
    }
  }
  mask[(size_t)row * 256 + tid] = word;
#pragma unroll
  for (int s = 1; s < 64; s <<= 1) ps += __shfl_xor(ps, s, 64);
  __shared__ float wsum[4];
  if ((tid & 63) == 0) wsum[tid >> 6] = ps;
  __syncthreads();
  if (tid == 0) {
    float l = wsum[0] + wsum[1] + wsum[2] + wsum[3];
    rinv[row] = (l > 0.f) ? (1.f / l) : 0.f;
  }
}

// ---- K5b: alpha writes + out = alpha@Wi (MFMA), mask from global bitmask
// grid 512 x 512 thr (8 waves). Block owns 16 u-rows. 33 KB LDS (epilogue only).
__global__ __launch_bounds__(512, 4) void k_mainB(
    const unsigned* __restrict__ mask, const float* __restrict__ a1g,
    const float* __restrict__ a2g, const float* __restrict__ mxp,
    const float* __restrict__ rinv, const short* __restrict__ WiT,
    float* __restrict__ outp, float* __restrict__ alphap)
{
  __shared__ __align__(16) float cop[4 * 2112];   // 4 copies x [16][132]
  const int tid  = threadIdx.x;
  const int lane = tid & 63;
  const int wvid = tid >> 6;
  const int u0 = blockIdx.x * ROWS;
  const int lr = lane & 15;
  const int lg = lane >> 4;
  const float A1 = a1g[u0 + lr];
  const float C  = lrelu(A1 + mxp[0]);
  const float ri = rinv[u0 + lr];
  const size_t arow = (size_t)(u0 + lr) * NI;
  const unsigned* mrow = mask + (size_t)(u0 + lr) * 256;
  fx4 acc[8];
#pragma unroll
  for (int n = 0; n < 8; ++n) acc[n] = (fx4){0.f, 0.f, 0.f, 0.f};

  for (int m = 0; m < 32; ++m) {
    const int ks = wvid + (m << 3);        // 0..255
    const int io = ks * 32 + lg * 8;
    bx8 bfr[8];
#pragma unroll
    for (int n = 0; n < 8; ++n)
      bfr[n] = *(const bx8*)(WiT + (size_t)(n * 16 + lr) * NI + io);
    const unsigned by = (mrow[ks] >> (lg * 8)) & 0xFFu;
    const fx4 aq0 = *(const fx4*)(a2g + io);
    const fx4 aq1 = *(const fx4*)(a2g + io + 4);
    float p[8];
#pragma unroll
    for (int j = 0; j < 8; ++j) {
      const float a2v = (j < 4) ? aq0[j] : aq1[j - 4];
      float e0 = __expf(lrelu(A1 + a2v) - C);
      p[j] = ((by >> j) & 1u) ? e0 : 0.f;
    }
    fx4 s0, s1;
#pragma unroll
    for (int j = 0; j < 4; ++j) { s0[j] = p[j] * ri; s1[j] = p[4 + j] * ri; }
    *(fx4*)(alphap + arow + io)     = s0;
    *(fx4*)(alphap + arow + io + 4) = s1;
    bx8 af;
#pragma unroll
    for (int j = 0; j < 8; ++j) af[j] = f2bf(p[j]);
#pragma unroll
    for (int n = 0; n < 8; ++n)
      acc[n] = __builtin_amdgcn_mfma_f32_16x16x32_bf16(af, bfr[n], acc[n], 0, 0, 0);
  }

  // ---- Epilogue: reduce 8 wave-partials via 4 LDS copies (stride-132 pad) ----
  float* my = cop + (size_t)(wvid & 3) * 2112;
  if (wvid < 4) {
#pragma unroll
    for (int n = 0; n < 8; ++n)
#pragma unroll
      for (int v = 0; v < 4; ++v)
        my[(lg * 4 + v) * 132 + n * 16 + lr] = acc[n][v];
  }
  __syncthreads();
  if (wvid >= 4) {
#pragma unroll
    for (int n = 0; n < 8; ++n)
#pragma unroll
      for (int v = 0; v < 4; ++v)
        my[(lg * 4 + v) * 132 + n * 16 + lr] += acc[n][v];
  }
  __syncthreads();
  {
    const int r  = tid >> 5;          // 0..15
    const int c0 = (tid & 31) * 4;    // 0..124
    const float ri_fin = rinv[u0 + r];
    fx4 s = *(const fx4*)(cop + r * 132 + c0);
#pragma unroll
    for (int c = 1; c < 4; ++c) {
      fx4 t = *(const fx4*)(cop + c * 2112 + r * 132 + c0);
      s[0] += t[0]; s[1] += t[1]; s[2] += t[2]; s[3] += t[3];
    }
    fx4 o;
#pragma unroll
    for (int e = 0; e < 4; ++e) o[e] = s[e] * ri_fin;
    *(fx4*)(outp + (size_t)(u0 + r) * DD + c0) = o;
  }
}

// ---- Fallback (ws too small for mask): round-2 fused kernel, unchanged math
__global__ __launch_bounds__(512, 4) void k_fused(
    const int* __restrict__ adj, const float* __restrict__ a1g,
    const float* __restrict__ a2g, const float* __restrict__ mxp,
    const short* __restrict__ WiT, float* __restrict__ outp,
    float* __restrict__ alphap)
{
  __shared__ __align__(16) char smem[34560];
  unsigned char* bytesl = (unsigned char*)smem;
  float* cop   = (float*)smem;
  float* Crow  = (float*)(smem + 33792);
  float* a1l   = (float*)(smem + 33856);
  float* rinvl = (float*)(smem + 33920);
  float* lpart = (float*)(smem + 33984);
  const int tid  = threadIdx.x;
  const int lane = tid & 63;
  const int wvid = tid >> 6;
  const int u0 = blockIdx.x * ROWS;
  const float mA2 = mxp[0];
  if (tid < ROWS) {
    float av = a1g[u0 + tid];
    a1l[tid]  = av;
    Crow[tid] = lrelu(av + mA2);
  }
  float a2r[16];
  {
    const fx4 q0 = *(const fx4*)(a2g + tid * 8);
    const fx4 q1 = *(const fx4*)(a2g + tid * 8 + 4);
    const fx4 q2 = *(const fx4*)(a2g + 4096 + tid * 8);
    const fx4 q3 = *(const fx4*)(a2g + 4096 + tid * 8 + 4);
#pragma unroll
    for (int e = 0; e < 4; ++e) {
      a2r[e] = q0[e]; a2r[4+e] = q1[e]; a2r[8+e] = q2[e]; a2r[12+e] = q3[e];
    }
  }
  __syncthreads();
  for (int r = 0; r < ROWS; ++r) {
    const float a1u = a1l[r];
    const float Cr  = Crow[r];
    const size_t rowbase = (size_t)(u0 + r) * NI;
    float ps = 0.f;
#pragma unroll
    for (int it = 0; it < 2; ++it) {
      const int ibase = it * 4096 + tid * 8;
      ix4 m0 = *(const ix4*)(adj + rowbase + ibase);
      ix4 m1 = *(const ix4*)(adj + rowbase + ibase + 4);
      unsigned byte = 0u;
#pragma unroll
      for (int e = 0; e < 8; ++e) {
        int mv = (e < 4) ? m0[e] : m1[e - 4];
        float p = __expf(lrelu(a1u + a2r[it * 8 + e]) - Cr);
        if (mv != 0) { ps += p; byte |= (1u << e); }
      }
      bytesl[r * 1028 + it * 512 + tid] = (unsigned char)byte;
    }
#pragma unroll
    for (int s = 1; s < 64; s <<= 1) ps += __shfl_xor(ps, s, 64);
    if (lane == 0) lpart[r * 8 + wvid] = ps;
  }
  __syncthreads();
  if (tid < ROWS) {
    float l = 0.f;
#pragma unroll
    for (int w = 0; w < 8; ++w) l += lpart[tid * 8 + w];
    rinvl[tid] = (l > 0.f) ? (1.f / l) : 0.f;
  }
  __syncthreads();
  const int lr = lane & 15;
  const int lg = lane >> 4;
  const float A1 = a1l[lr], C = Crow[lr], ri = rinvl[lr];
  const size_t arow = (size_t)(u0 + lr) * NI;
  fx4 acc[8];
#pragma unroll
  for (int n = 0; n < 8; ++n) acc[n] = (fx4){0.f, 0.f, 0.f, 0.f};
  for (int m = 0; m < 32; ++m) {
    const int ks = wvid + (m << 3);
    const int io = ks * 32 + lg * 8;
    bx8 bfr[8];
#pragma unroll
    for (int n = 0; n < 8; ++n)
      bfr[n] = *(const bx8*)(WiT + (size_t)(n * 16 + lr) * NI + io);
    const unsigned wmask = *(const unsigned*)(bytesl + lr * 1028 + ks * 4);
    const unsigned by = (wmask >> (lg * 8)) & 0xFFu;
    const fx4 aq0 = *(const fx4*)(a2g + io);
    const fx4 aq1 = *(const fx4*)(a2g + io + 4);
    float p[8];
#pragma unroll
    for (int j = 0; j < 8; ++j) {
      const float a2v = (j < 4) ? aq0[j] : aq1[j - 4];
      float e0 = __expf(lrelu(A1 + a2v) - C);
      p[j] = ((by >> j) & 1u) ? e0 : 0.f;
    }
    fx4 s0, s1;
#pragma unroll
    for (int j = 0; j < 4; ++j) { s0[j] = p[j] * ri; s1[j] = p[4 + j] * ri; }
    *(fx4*)(alphap + arow + io)     = s0;
    *(fx4*)(alphap + arow + io + 4) = s1;
    bx8 af;
#pragma unroll
    for (int j = 0; j < 8; ++j) af[j] = f2bf(p[j]);
#pragma unroll
    for (int n = 0; n < 8; ++n)
      acc[n] = __builtin_amdgcn_mfma_f32_16x16x32_bf16(af, bfr[n], acc[n], 0, 0, 0);
  }
  const float ri_fin = rinvl[tid >> 5];
  __syncthreads();
  float* my = cop + (size_t)(wvid & 3) * 2112;
  if (wvid < 4) {
#pragma unroll
    for (int n = 0; n < 8; ++n)
#pragma unroll
      for (int v = 0; v < 4; ++v)
        my[(lg * 4 + v) * 132 + n * 16 + lr] = acc[n][v];
  }
  __syncthreads();
  if (wvid >= 4) {
#pragma unroll
    for (int n = 0; n < 8; ++n)
#pragma unroll
      for (int v = 0; v < 4; ++v)
        my[(lg * 4 + v) * 132 + n * 16 + lr] += acc[n][v];
  }
  __syncthreads();
  {
    const int r  = tid >> 5;
    const int c0 = (tid & 31) * 4;
    fx4 s = *(const fx4*)(cop + r * 132 + c0);
#pragma unroll
    for (int c = 1; c < 4; ++c) {
      fx4 t = *(const fx4*)(cop + c * 2112 + r * 132 + c0);
      s[0] += t[0]; s[1] += t[1]; s[2] += t[2]; s[3] += t[3];
    }
    fx4 o;
#pragma unroll
    for (int e = 0; e < 4; ++e) o[e] = s[e] * ri_fin;
    *(fx4*)(outp + (size_t)(u0 + r) * DD + c0) = o;
  }
}

extern "C" void kernel_launch(void* const* d_in, const int* in_sizes, int n_in,
                              void* d_out, int out_size, void* d_ws, size_t ws_size,
                              hipStream_t stream) {
  (void)in_sizes; (void)n_in; (void)out_size;
  const float* h_u = (const float*)d_in[0];
  const float* h_i = (const float*)d_in[1];
  const int*   adj = (const int*)d_in[2];
  const float* W   = (const float*)d_in[3];
  const float* a   = (const float*)d_in[4];

  float* outp   = (float*)d_out;                       // [8192][128]
  float* alphap = (float*)d_out + (size_t)NU * DD;     // [8192][8192]

  char* ws = (char*)d_ws;
  float*    v1   = (float*)(ws + 0);         // 128 f32
  float*    v2   = (float*)(ws + 512);       // 128 f32
  float*    mx   = (float*)(ws + 1024);      // 1 f32
  float*    a1   = (float*)(ws + 4096);      // 8192 f32
  float*    a2   = (float*)(ws + 36864);     // 8192 f32
  float*    rinv = (float*)(ws + 69632);     // 8192 f32
  short*    WiT  = (short*)(ws + 131072);    // 128*8192 bf16 = 2 MiB
  unsigned* mask = (unsigned*)(ws + 2228224);// 8192*256 u32 = 8 MiB

  k_vecs   <<<1,   128, 0, stream>>>(W, a, v1, v2);
  k_rowdots<<<64,  256, 0, stream>>>(h_u, h_i, v1, v2, a1, a2);
  k_maxa2  <<<1,   256, 0, stream>>>(a2, mx);
  k_wit    <<<128, 256, 0, stream>>>(h_i, W, WiT);

  if (ws_size >= (size_t)2228224 + (size_t)NU * 256 * sizeof(unsigned)) {
    k_phaseA<<<NU,  256, 0, stream>>>(adj, a1, a2, mx, rinv, mask);
    k_mainB <<<512, 512, 0, stream>>>(mask, a1, a2, mx, rinv, WiT, outp, alphap);
  } else {
    k_fused <<<512, 512, 0, stream>>>(adj, a1, a2, mx, WiT, outp, alphap);
  }
}

// Round 4
// 307.178 us; speedup vs baseline: 1.0513x; 1.0513x over previous
//
#include <hip/hip_runtime.h>

#define NU 8192
#define NI 8192
#define DD 128

typedef float fx4 __attribute__((ext_vector_type(4)));
typedef int   ix4 __attribute__((ext_vector_type(4)));
typedef short bx8 __attribute__((ext_vector_type(8)));
typedef short sx4 __attribute__((ext_vector_type(4)));

__device__ __forceinline__ short f2bf(float f) {
  unsigned u = __float_as_uint(f);
  u = (u + 0x7FFFu + ((u >> 16) & 1u)) >> 16;   // RNE f32 -> bf16
  return (short)u;
}
__device__ __forceinline__ float lrelu(float x) { return fmaxf(x, 0.2f * x); }
// order-preserving float<->uint encode for atomicMax
__device__ __forceinline__ unsigned fenc(float f) {
  unsigned u = __float_as_uint(f);
  return (u >> 31) ? ~u : (u | 0x80000000u);
}
__device__ __forceinline__ float fdec(unsigned u) {
  return (u >> 31) ? __uint_as_float(u & 0x7FFFFFFFu) : __uint_as_float(~u);
}

// ---- K1: v1[j] = sum_k a[k]*W[k][j] ; v2[j] = sum_k a[128+k]*W[k][j]; init mxenc
__global__ void k_vecs(const float* __restrict__ W, const float* __restrict__ a,
                       float* __restrict__ v1, float* __restrict__ v2,
                       unsigned* __restrict__ mxenc) {
  int j = threadIdx.x;  // 128 threads
  if (j == 0) mxenc[0] = 0u;   // < fenc(any finite float)
  float s1 = 0.f, s2 = 0.f;
  for (int k = 0; k < DD; ++k) {
    float w = W[k * DD + j];
    s1 += a[k] * w;
    s2 += a[DD + k] * w;
  }
  v1[j] = s1; v2[j] = s2;
}

// ---- K2: a1[u]=h_u·v1 ; a2[i]=h_i·v2 ; E1=exp(a2), E2=exp(0.2 a2); atomicMax a2
__global__ __launch_bounds__(256) void k_rowdots(
    const float* __restrict__ hU, const float* __restrict__ hI,
    const float* __restrict__ v1, const float* __restrict__ v2,
    float* __restrict__ a1, float* __restrict__ a2,
    float* __restrict__ e1, float* __restrict__ e2,
    unsigned* __restrict__ mxenc) {
  __shared__ float red[256];
  int g = blockIdx.x * 256 + threadIdx.x;
  const float* h; const float* v; int row;
  bool isU = (g < NU);
  if (isU) { h = hU; v = v1; row = g; }
  else     { h = hI; v = v2; row = g - NU; }
  const fx4* hv = (const fx4*)(h + (size_t)row * DD);
  const fx4* vv = (const fx4*)v;
  float s = 0.f;
#pragma unroll
  for (int q = 0; q < DD / 4; ++q) {
    fx4 hq = hv[q], vq = vv[q];
    s += hq[0]*vq[0] + hq[1]*vq[1] + hq[2]*vq[2] + hq[3]*vq[3];
  }
  if (isU) { a1[row] = s; return; }           // blocks 0..31 all-user: uniform exit
  a2[row] = s;
  e1[row] = __expf(s);
  e2[row] = __expf(0.2f * s);
  red[threadIdx.x] = s;
  __syncthreads();
  for (int st = 128; st > 0; st >>= 1) {
    if (threadIdx.x < st) red[threadIdx.x] = fmaxf(red[threadIdx.x], red[threadIdx.x + st]);
    __syncthreads();
  }
  if (threadIdx.x == 0) atomicMax(mxenc, fenc(red[0]));
}

// ---- K4: WiT[k][i] (bf16) = Wi[i][k] = sum_j h_i[i][j]*W[k][j]
__global__ __launch_bounds__(256) void k_wit(const float* __restrict__ hI,
                                             const float* __restrict__ W,
                                             short* __restrict__ WiT) {
  __shared__ float Wl[128 * 128];
  const int tid = threadIdx.x;
#pragma unroll
  for (int it = 0; it < 16; ++it) {
    int idx = it * 1024 + tid * 4;
    *(fx4*)(Wl + idx) = *(const fx4*)(W + idx);
  }
  __syncthreads();
  const int i0 = blockIdx.x * 64;
  const int rg = tid & 15;
  const int kg = tid >> 4;
  const int r0 = i0 + rg * 4;
  const int k0 = kg * 8;
  float acc[4][8];
#pragma unroll
  for (int r = 0; r < 4; ++r)
#pragma unroll
    for (int c = 0; c < 8; ++c) acc[r][c] = 0.f;
  for (int j = 0; j < 128; j += 4) {
    fx4 wv[8], hv[4];
#pragma unroll
    for (int c = 0; c < 8; ++c) wv[c] = *(const fx4*)(Wl + (k0 + c) * 128 + j);
#pragma unroll
    for (int r = 0; r < 4; ++r) hv[r] = *(const fx4*)(hI + (size_t)(r0 + r) * DD + j);
#pragma unroll
    for (int r = 0; r < 4; ++r)
#pragma unroll
      for (int c = 0; c < 8; ++c)
        acc[r][c] += hv[r][0]*wv[c][0] + hv[r][1]*wv[c][1] + hv[r][2]*wv[c][2] + hv[r][3]*wv[c][3];
  }
#pragma unroll
  for (int c = 0; c < 8; ++c) {
    sx4 pk;
#pragma unroll
    for (int r = 0; r < 4; ++r) pk[r] = f2bf(acc[r][c]);
    *(sx4*)(WiT + (size_t)(k0 + c) * NI + r0) = pk;
  }
}

// ---- K5a: stream adj once -> bitmask[8192][256] + rinv[8192]; no transcendentals
// grid 4096, 256 thr; block owns 2 rows; thread owns i in [tid*32, tid*32+32)
__global__ __launch_bounds__(256, 4) void k_phaseA(
    const int* __restrict__ adj, const float* __restrict__ a1g,
    const float* __restrict__ e1g, const float* __restrict__ e2g,
    const unsigned* __restrict__ mxenc,
    float* __restrict__ rinv, unsigned* __restrict__ mask)
{
  const int tid  = threadIdx.x;
  const int lane = tid & 63;
  const int wv   = tid >> 6;        // 0..3
  const int r0   = blockIdx.x * 2;
  const float mA2 = fdec(mxenc[0]);
  const int i0 = tid * 32;
  fx4 E1[8], E2[8];
#pragma unroll
  for (int q = 0; q < 8; ++q) {
    E1[q] = *(const fx4*)(e1g + i0 + q * 4);
    E2[q] = *(const fx4*)(e2g + i0 + q * 4);
  }
  __shared__ float lpart[2][4];
#pragma unroll
  for (int r = 0; r < 2; ++r) {
    const int row = r0 + r;
    const float A  = a1g[row];
    const float C  = lrelu(A + mA2);
    const float K1 = __expf(A - C);
    const float K2 = __expf(0.2f * A - C);
    const float T1 = __expf(-A);          // sel <=> E1[i] > T1 <=> a1+a2 > 0
    const size_t base = (size_t)row * NI + i0;
    ix4 m[8];
#pragma unroll
    for (int q = 0; q < 8; ++q) m[q] = *(const ix4*)(adj + base + q * 4);
    unsigned word = 0u;
    float s1 = 0.f, s2 = 0.f;
#pragma unroll
    for (int q = 0; q < 8; ++q) {
#pragma unroll
      for (int e = 0; e < 4; ++e) {
        const bool mm = (m[q][e] != 0);
        const float e1v = E1[q][e], e2v = E2[q][e];
        const bool sel = (e1v > T1);
        if (mm) word |= (1u << (q * 4 + e));
        s1 += (mm && sel)  ? e1v : 0.f;
        s2 += (mm && !sel) ? e2v : 0.f;
      }
    }
    mask[(size_t)row * 256 + tid] = word;
    float ps = K1 * s1 + K2 * s2;
#pragma unroll
    for (int st = 1; st < 64; st <<= 1) ps += __shfl_xor(ps, st, 64);
    if (lane == 0) lpart[r][wv] = ps;
  }
  __syncthreads();
  if (tid < 2) {
    float l = lpart[tid][0] + lpart[tid][1] + lpart[tid][2] + lpart[tid][3];
    rinv[r0 + tid] = (l > 0.f) ? (1.f / l) : 0.f;
  }
}

// ---- K5b: chunked alpha + out = alpha@Wi.
// grid 512 x 512 thr (8 waves); block owns 16 rows; 16 chunks of 512 i.
// S1: wave w computes alpha rows 2w,2w+1 (contiguous 2KB runs) + bf16 P -> LDS (swz)
// S2: all waves MFMA from LDS A-frags vs WiT; acc across chunks; epilogue reduce.
__global__ __launch_bounds__(512, 4) void k_mainB(
    const unsigned* __restrict__ mask, const float* __restrict__ a1g,
    const float* __restrict__ e1g, const float* __restrict__ e2g,
    const unsigned* __restrict__ mxenc, const float* __restrict__ rinv,
    const short* __restrict__ WiT, float* __restrict__ outp,
    float* __restrict__ alphap)
{
  __shared__ __align__(16) char smem[34560];  // 2x16KB P bufs; reused as 33792B cop
  const int tid  = threadIdx.x;
  const int lane = tid & 63;
  const int wv   = tid >> 6;
  const int u0 = blockIdx.x * 16;
  const float mA2 = fdec(mxenc[0]);
  const int lr = lane & 15;
  const int lg = lane >> 4;

  // wave's two alpha rows
  const int rA = wv * 2;
  float KA1[2], KA2[2], T1r[2];
  size_t arow[2];
  const unsigned* mrow[2];
#pragma unroll
  for (int t = 0; t < 2; ++t) {
    const int row = u0 + rA + t;
    const float A = a1g[row];
    const float C = lrelu(A + mA2);
    const float ri = rinv[row];
    KA1[t] = __expf(A - C) * ri;          // alpha = sel? E1*KA1 : E2*KA2 (pre-normalized)
    KA2[t] = __expf(0.2f * A - C) * ri;
    T1r[t] = __expf(-A);
    arow[t] = (size_t)row * NI;
    mrow[t] = mask + (size_t)row * 256;
  }
  fx4 acc[8];
#pragma unroll
  for (int n = 0; n < 8; ++n) acc[n] = (fx4){0.f, 0.f, 0.f, 0.f};

  for (int c = 0; c < 16; ++c) {
    char* buf = smem + (c & 1) * 16384;
    const int ib = c * 512 + lane * 8;
    // shared E chunk (same for both rows)
    const fx4 e1a = *(const fx4*)(e1g + ib);
    const fx4 e1b = *(const fx4*)(e1g + ib + 4);
    const fx4 e2a = *(const fx4*)(e2g + ib);
    const fx4 e2b = *(const fx4*)(e2g + ib + 4);
#pragma unroll
    for (int t = 0; t < 2; ++t) {
      const int rl = rA + t;
      const unsigned mword = mrow[t][c * 16 + (lane >> 2)];
      const unsigned mb = (mword >> ((lane & 3) * 8)) & 0xFFu;
      float pv[8];
#pragma unroll
      for (int j = 0; j < 8; ++j) {
        const float e1v = (j < 4) ? e1a[j] : e1b[j - 4];
        const float e2v = (j < 4) ? e2a[j] : e2b[j - 4];
        const float val = (e1v > T1r[t]) ? e1v * KA1[t] : e2v * KA2[t];
        pv[j] = ((mb >> j) & 1u) ? val : 0.f;
      }
      fx4 s0, s1;
#pragma unroll
      for (int j = 0; j < 4; ++j) { s0[j] = pv[j]; s1[j] = pv[4 + j]; }
      *(fx4*)(alphap + arow[t] + ib)     = s0;   // 2KB contiguous per wave per row
      *(fx4*)(alphap + arow[t] + ib + 4) = s1;
      bx8 af;
#pragma unroll
      for (int j = 0; j < 8; ++j) af[j] = f2bf(pv[j]);
      *(bx8*)(buf + rl * 1024 + ((lane * 16) ^ ((rl & 7) << 4))) = af;
    }
    __syncthreads();
    // S2: 2 k-steps per wave from this chunk
#pragma unroll
    for (int t2 = 0; t2 < 2; ++t2) {
      const int kl = wv + t2 * 8;                 // 0..15 local k-step
      const bx8 afr = *(const bx8*)(buf + lr * 1024 +
                                    (((kl * 64) + lg * 16) ^ ((lr & 7) << 4)));
      const int io = (c * 16 + kl) * 32 + lg * 8;
      bx8 bfr[8];
#pragma unroll
      for (int n = 0; n < 8; ++n)
        bfr[n] = *(const bx8*)(WiT + (size_t)(n * 16 + lr) * NI + io);
#pragma unroll
      for (int n = 0; n < 8; ++n)
        acc[n] = __builtin_amdgcn_mfma_f32_16x16x32_bf16(afr, bfr[n], acc[n], 0, 0, 0);
    }
  }

  // ---- Epilogue: reduce 8 wave-partials via 4 LDS copies (stride-132); no ri (folded)
  __syncthreads();
  float* cop = (float*)smem;
  float* my = cop + (size_t)(wv & 3) * 2112;
  if (wv < 4) {
#pragma unroll
    for (int n = 0; n < 8; ++n)
#pragma unroll
      for (int v = 0; v < 4; ++v)
        my[(lg * 4 + v) * 132 + n * 16 + lr] = acc[n][v];
  }
  __syncthreads();
  if (wv >= 4) {
#pragma unroll
    for (int n = 0; n < 8; ++n)
#pragma unroll
      for (int v = 0; v < 4; ++v)
        my[(lg * 4 + v) * 132 + n * 16 + lr] += acc[n][v];
  }
  __syncthreads();
  {
    const int r  = tid >> 5;          // 0..15
    const int c0 = (tid & 31) * 4;    // 0..124
    fx4 s = *(const fx4*)(cop + r * 132 + c0);
#pragma unroll
    for (int cc = 1; cc < 4; ++cc) {
      fx4 t = *(const fx4*)(cop + cc * 2112 + r * 132 + c0);
      s[0] += t[0]; s[1] += t[1]; s[2] += t[2]; s[3] += t[3];
    }
    *(fx4*)(outp + (size_t)(u0 + r) * DD + c0) = s;
  }
}

// ---- Fallback (ws too small for mask): fused kernel (round-2 proven path)
__global__ __launch_bounds__(512, 4) void k_fused(
    const int* __restrict__ adj, const float* __restrict__ a1g,
    const float* __restrict__ a2g, const unsigned* __restrict__ mxenc,
    const short* __restrict__ WiT, float* __restrict__ outp,
    float* __restrict__ alphap)
{
  __shared__ __align__(16) char smem[34560];
  unsigned char* bytesl = (unsigned char*)smem;
  float* cop   = (float*)smem;
  float* Crow  = (float*)(smem + 33792);
  float* a1l   = (float*)(smem + 33856);
  float* rinvl = (float*)(smem + 33920);
  float* lpart = (float*)(smem + 33984);
  const int tid  = threadIdx.x;
  const int lane = tid & 63;
  const int wvid = tid >> 6;
  const int u0 = blockIdx.x * 16;
  const float mA2 = fdec(mxenc[0]);
  if (tid < 16) {
    float av = a1g[u0 + tid];
    a1l[tid]  = av;
    Crow[tid] = lrelu(av + mA2);
  }
  float a2r[16];
  {
    const fx4 q0 = *(const fx4*)(a2g + tid * 8);
    const fx4 q1 = *(const fx4*)(a2g + tid * 8 + 4);
    const fx4 q2 = *(const fx4*)(a2g + 4096 + tid * 8);
    const fx4 q3 = *(const fx4*)(a2g + 4096 + tid * 8 + 4);
#pragma unroll
    for (int e = 0; e < 4; ++e) {
      a2r[e] = q0[e]; a2r[4+e] = q1[e]; a2r[8+e] = q2[e]; a2r[12+e] = q3[e];
    }
  }
  __syncthreads();
  for (int r = 0; r < 16; ++r) {
    const float a1u = a1l[r];
    const float Cr  = Crow[r];
    const size_t rowbase = (size_t)(u0 + r) * NI;
    float ps = 0.f;
#pragma unroll
    for (int it = 0; it < 2; ++it) {
      const int ibase = it * 4096 + tid * 8;
      ix4 m0 = *(const ix4*)(adj + rowbase + ibase);
      ix4 m1 = *(const ix4*)(adj + rowbase + ibase + 4);
      unsigned byte = 0u;
#pragma unroll
      for (int e = 0; e < 8; ++e) {
        int mv = (e < 4) ? m0[e] : m1[e - 4];
        float p = __expf(lrelu(a1u + a2r[it * 8 + e]) - Cr);
        if (mv != 0) { ps += p; byte |= (1u << e); }
      }
      bytesl[r * 1028 + it * 512 + tid] = (unsigned char)byte;
    }
#pragma unroll
    for (int s = 1; s < 64; s <<= 1) ps += __shfl_xor(ps, s, 64);
    if (lane == 0) lpart[r * 8 + wvid] = ps;
  }
  __syncthreads();
  if (tid < 16) {
    float l = 0.f;
#pragma unroll
    for (int w = 0; w < 8; ++w) l += lpart[tid * 8 + w];
    rinvl[tid] = (l > 0.f) ? (1.f / l) : 0.f;
  }
  __syncthreads();
  const int lr = lane & 15;
  const int lg = lane >> 4;
  const float A1 = a1l[lr], C = Crow[lr], ri = rinvl[lr];
  const size_t arow = (size_t)(u0 + lr) * NI;
  fx4 acc[8];
#pragma unroll
  for (int n = 0; n < 8; ++n) acc[n] = (fx4){0.f, 0.f, 0.f, 0.f};
  for (int m = 0; m < 32; ++m) {
    const int ks = wvid + (m << 3);
    const int io = ks * 32 + lg * 8;
    bx8 bfr[8];
#pragma unroll
    for (int n = 0; n < 8; ++n)
      bfr[n] = *(const bx8*)(WiT + (size_t)(n * 16 + lr) * NI + io);
    const unsigned wmask = *(const unsigned*)(bytesl + lr * 1028 + ks * 4);
    const unsigned by = (wmask >> (lg * 8)) & 0xFFu;
    const fx4 aq0 = *(const fx4*)(a2g + io);
    const fx4 aq1 = *(const fx4*)(a2g + io + 4);
    float p[8];
#pragma unroll
    for (int j = 0; j < 8; ++j) {
      const float a2v = (j < 4) ? aq0[j] : aq1[j - 4];
      float e0 = __expf(lrelu(A1 + a2v) - C);
      p[j] = ((by >> j) & 1u) ? e0 : 0.f;
    }
    fx4 s0, s1;
#pragma unroll
    for (int j = 0; j < 4; ++j) { s0[j] = p[j] * ri; s1[j] = p[4 + j] * ri; }
    *(fx4*)(alphap + arow + io)     = s0;
    *(fx4*)(alphap + arow + io + 4) = s1;
    bx8 af;
#pragma unroll
    for (int j = 0; j < 8; ++j) af[j] = f2bf(p[j]);
#pragma unroll
    for (int n = 0; n < 8; ++n)
      acc[n] = __builtin_amdgcn_mfma_f32_16x16x32_bf16(af, bfr[n], acc[n], 0, 0, 0);
  }
  const float ri_fin = rinvl[tid >> 5];
  __syncthreads();
  float* my = cop + (size_t)(wvid & 3) * 2112;
  if (wvid < 4) {
#pragma unroll
    for (int n = 0; n < 8; ++n)
#pragma unroll
      for (int v = 0; v < 4; ++v)
        my[(lg * 4 + v) * 132 + n * 16 + lr] = acc[n][v];
  }
  __syncthreads();
  if (wvid >= 4) {
#pragma unroll
    for (int n = 0; n < 8; ++n)
#pragma unroll
      for (int v = 0; v < 4; ++v)
        my[(lg * 4 + v) * 132 + n * 16 + lr] += acc[n][v];
  }
  __syncthreads();
  {
    const int r  = tid >> 5;
    const int c0 = (tid & 31) * 4;
    fx4 s = *(const fx4*)(cop + r * 132 + c0);
#pragma unroll
    for (int cc = 1; cc < 4; ++cc) {
      fx4 t = *(const fx4*)(cop + cc * 2112 + r * 132 + c0);
      s[0] += t[0]; s[1] += t[1]; s[2] += t[2]; s[3] += t[3];
    }
    fx4 o;
#pragma unroll
    for (int e = 0; e < 4; ++e) o[e] = s[e] * ri_fin;
    *(fx4*)(outp + (size_t)(u0 + r) * DD + c0) = o;
  }
}

extern "C" void kernel_launch(void* const* d_in, const int* in_sizes, int n_in,
                              void* d_out, int out_size, void* d_ws, size_t ws_size,
                              hipStream_t stream) {
  (void)in_sizes; (void)n_in; (void)out_size;
  const float* h_u = (const float*)d_in[0];
  const float* h_i = (const float*)d_in[1];
  const int*   adj = (const int*)d_in[2];
  const float* W   = (const float*)d_in[3];
  const float* a   = (const float*)d_in[4];

  float* outp   = (float*)d_out;                       // [8192][128]
  float* alphap = (float*)d_out + (size_t)NU * DD;     // [8192][8192]

  char* ws = (char*)d_ws;
  float*    v1    = (float*)(ws + 0);          // 128 f32
  float*    v2    = (float*)(ws + 512);        // 128 f32
  unsigned* mxenc = (unsigned*)(ws + 1024);    // 1 u32 (order-encoded max a2)
  float*    a1    = (float*)(ws + 4096);       // 8192 f32
  float*    a2    = (float*)(ws + 36864);      // 8192 f32
  float*    rinv  = (float*)(ws + 69632);      // 8192 f32
  float*    e1t   = (float*)(ws + 102400);     // 8192 f32: exp(a2)
  float*    e2t   = (float*)(ws + 135168);     // 8192 f32: exp(0.2 a2)
  short*    WiT   = (short*)(ws + 262144);     // 128*8192 bf16 = 2 MiB
  unsigned* mask  = (unsigned*)(ws + 2359296); // 8192*256 u32 = 8 MiB

  k_vecs   <<<1,  128, 0, stream>>>(W, a, v1, v2, mxenc);
  k_rowdots<<<64, 256, 0, stream>>>(h_u, h_i, v1, v2, a1, a2, e1t, e2t, mxenc);
  k_wit    <<<128, 256, 0, stream>>>(h_i, W, WiT);

  if (ws_size >= (size_t)2359296 + (size_t)NU * 256 * sizeof(unsigned)) {
    k_phaseA<<<NU / 2, 256, 0, stream>>>(adj, a1, e1t, e2t, mxenc, rinv, mask);
    k_mainB <<<512,    512, 0, stream>>>(mask, a1, e1t, e2t, mxenc, rinv, WiT, outp, alphap);
  } else {
    k_fused <<<512,    512, 0, stream>>>(adj, a1, a2, mxenc, WiT, outp, alphap);
  }
}